// Round 15
// baseline (166.499 us; speedup 1.0000x reference)
//
#include <hip/hip_runtime.h>
#include <math.h>

// Problem constants
#define NBATCH 4
#define NCLS   19
#define HWDIM  512
#define HW     (512 * 512)      // 262144
#define PH     171              // pooled H=W
#define PHP    176              // padded row stride (16B-aligned rows)
#define PP2A   (171 * 176)      // 30096 floats per (n,c) plane
#define NHW    169              // PH - radius + 1
#define MM     (169 * 169)      // 28561

typedef float f4  __attribute__((ext_vector_type(4)));
typedef float f2v __attribute__((ext_vector_type(2)));

// ---------------------------------------------------------------------------
// Stage 1 (round-6/9 measured-best, verbatim): fused softmax + one-hot +
// 3x3/stride-3 avg-pool (pad=1, /9). One block per (n, pooled-row ph).
// ---------------------------------------------------------------------------
__global__ __launch_bounds__(512) void stage1_pool(
    const float* __restrict__ cls, const int* __restrict__ label,
    float* __restrict__ P, float* __restrict__ L) {
  int n  = blockIdx.x / PH;
  int ph = blockIdx.x - n * PH;
  int col = threadIdx.x;  // input column 0..511

  float vv[3][NCLS];
  int lbs[3];
#pragma unroll
  for (int i = 0; i < 3; ++i) {
    int r = 3 * ph - 1 + i;
    bool ok = (r >= 0) && (r < HWDIM);  // wave-uniform
    if (ok) {
      lbs[i] = label[((size_t)n * HWDIM + r) * HWDIM + col];
      const float* base = cls + (size_t)n * NCLS * HW + (size_t)r * HWDIM + col;
#pragma unroll
      for (int c = 0; c < NCLS; ++c) vv[i][c] = base[(size_t)c * HW];
    } else {
      lbs[i] = -1;
#pragma unroll
      for (int c = 0; c < NCLS; ++c) vv[i][c] = 0.f;
    }
  }

  float accP[NCLS], accL[NCLS];
#pragma unroll
  for (int c = 0; c < NCLS; ++c) { accP[c] = 0.f; accL[c] = 0.f; }
#pragma unroll
  for (int i = 0; i < 3; ++i) {
    int lb = lbs[i];
    float mx = vv[i][0];
#pragma unroll
    for (int c = 1; c < NCLS; ++c) mx = fmaxf(mx, vv[i][c]);
    float se = 0.f;
    float ex[NCLS];
#pragma unroll
    for (int c = 0; c < NCLS; ++c) {
      ex[c] = __expf(vv[i][c] - mx);
      se += ex[c];
    }
    float m = (lb >= 0 && lb < NCLS) ? 1.f : 0.f;
    float inv = m / se;
#pragma unroll
    for (int c = 0; c < NCLS; ++c) {
      accP[c] += ex[c] * inv;
      accL[c] += (lb == c) ? 1.f : 0.f;  // compile-time index
    }
  }

  __shared__ float xbP[10][516];
  __shared__ float xbL[10][516];
  const float inv9 = 1.f / 9.f;
#pragma unroll
  for (int c0 = 0; c0 < NCLS; c0 += 10) {
#pragma unroll
    for (int cc = 0; cc < 10; ++cc) {
      if (c0 + cc < NCLS) {
        xbP[cc][1 + col] = accP[(c0 + cc) < NCLS ? (c0 + cc) : 0];
        xbL[cc][1 + col] = accL[(c0 + cc) < NCLS ? (c0 + cc) : 0];
        if (col == 0) { xbP[cc][0] = 0.f; xbL[cc][0] = 0.f; }
      }
    }
    __syncthreads();
    if (col < PH) {
      int pw = col;
#pragma unroll
      for (int cc = 0; cc < 10; ++cc) {
        if (c0 + cc < NCLS) {
          int c = c0 + cc;
          float sP = xbP[cc][3 * pw] + xbP[cc][3 * pw + 1] + xbP[cc][3 * pw + 2];
          float sL = xbL[cc][3 * pw] + xbL[cc][3 * pw + 1] + xbL[cc][3 * pw + 2];
          size_t o = ((size_t)(n * NCLS + c)) * PP2A + (size_t)ph * PHP + pw;
          P[o] = sP * inv9;
          L[o] = sL * inv9;
        }
      }
    } else if (col < PHP) {
#pragma unroll
      for (int cc = 0; cc < 10; ++cc) {
        if (c0 + cc < NCLS) {
          int c = c0 + cc;
          size_t o = ((size_t)(n * NCLS + c)) * PP2A + (size_t)ph * PHP + col;
          P[o] = 0.f;
          L[o] = 0.f;
        }
      }
    }
    __syncthreads();
  }
}

// ---------------------------------------------------------------------------
// Stage 2 (round-9 measured-best, verbatim): packed-fp32 moments with
// zero-move 4-slot window rotation. Parts: 0: la*la+sum(la) | 1: pr*pr+sum(pr)
// | 2: pr[d]*la[e]. Record per nc (stride 192 f32): [0..8] sum la |
// [9..17] sum pr | [18..62] la*la | [63..107] pr*pr | [108..188] pr*la |
// [190..191] (double) logdet from stage3
// NOTE: pure idempotent function (P,L)->cov; this round launches it 4x for
// direct time attribution (s2 = (dur - 72.5)/3).
// ---------------------------------------------------------------------------
template <int MODE, int NA>
__device__ __forceinline__ void epilogue(const f2v (&acc2)[NA], float* red,
                                         float* __restrict__ covp, int nc) {
  int lane = threadIdx.x & 63;
  int wid  = threadIdx.x >> 6;  // 8 waves
#pragma unroll
  for (int k = 0; k < NA; ++k) {
    float v = acc2[k].x + acc2[k].y;
    v += __shfl_down(v, 32, 64);
    v += __shfl_down(v, 16, 64);
    v += __shfl_down(v, 8, 64);
    if (lane < 8) red[(wid * 8 + lane) * 84 + k] = v;
  }
  __syncthreads();
  int tid = threadIdx.x;
  if (tid < NA) {
    float sm = 0.f;
#pragma unroll
    for (int w = 0; w < 64; ++w) sm += red[w * 84 + tid];
    int off;
    if (MODE == 0)      off = (tid < 9) ? tid : 18 + (tid - 9);
    else if (MODE == 1) off = (tid < 9) ? 9 + tid : 63 + (tid - 9);
    else                off = 108 + tid;
    covp[(size_t)nc * 192 + off] = sm;
  }
}

__device__ __forceinline__ void fma_self_triple(f2v (&acc2)[54],
    const f2v (&r0)[5], const f2v (&r1)[5], const f2v (&r2)[5]) {
#define RP(d, off) ((d) < 3 ? r0[(d) % 3 + (off)] \
                 : (d) < 6 ? r1[(d) % 3 + (off)] : r2[(d) % 3 + (off)])
#pragma unroll
  for (int d = 0; d < 9; ++d) {
    acc2[d] += RP(d, 0);
    acc2[d] += RP(d, 2);
  }
  {
    int k = 9;
#pragma unroll
    for (int d = 0; d < 9; ++d)
#pragma unroll
      for (int e = d; e < 9; ++e) {
        acc2[k] += RP(d, 0) * RP(e, 0);
        acc2[k] += RP(d, 2) * RP(e, 2);
        ++k;
      }
  }
#undef RP
}

__device__ __forceinline__ void fma_cross_triple(f2v (&acc2)[81],
    const f2v (&p0)[3], const f2v (&p1)[3], const f2v (&p2)[3],
    const f2v (&l0)[3], const f2v (&l1)[3], const f2v (&l2)[3]) {
#define QP(d) ((d) < 3 ? p0[(d) % 3] : (d) < 6 ? p1[(d) % 3] : p2[(d) % 3])
#define QL(e) ((e) < 3 ? l0[(e) % 3] : (e) < 6 ? l1[(e) % 3] : l2[(e) % 3])
#pragma unroll
  for (int d = 0; d < 9; ++d)
#pragma unroll
    for (int e = 0; e < 9; ++e)
      acc2[d * 9 + e] += QP(d) * QL(e);
#undef QP
#undef QL
}

// ---- A/B: self moments, strips of 4 positions; 42x11 full + 11 tail ----
template <int MODE>
__device__ __forceinline__ void mom_self(const float* __restrict__ X,
                                         float* __restrict__ covp, int nc,
                                         float* red) {
  f2v acc2[54];
#pragma unroll
  for (int k = 0; k < 54; ++k) acc2[k] = (f2v){0.f, 0.f};

  int tid = threadIdx.x;
  if (tid < 462) {
    int b = tid / 42, s = tid - b * 42;
    int x0 = 4 * s;  // 0..164
    int y0 = (NHW * b) / 11;
    int y1 = (NHW * (b + 1)) / 11;

    f2v s0[5], s1[5], s2[5], s3[5];
    auto ldr = [&](f2v (&dst)[5], int row) {
      if (row > PH - 1) row = PH - 1;  // clamp; clamped rows never consumed
      f4  a  = *(const f4*)(X + row * PHP + x0);
      f2v bb = *(const f2v*)(X + row * PHP + x0 + 4);
      dst[0] = (f2v){a.x, a.y}; dst[1] = (f2v){a.y, a.z};
      dst[2] = (f2v){a.z, a.w}; dst[3] = (f2v){a.w, bb.x};
      dst[4] = bb;
    };
    ldr(s0, y0); ldr(s1, y0 + 1); ldr(s2, y0 + 2);

    int y = y0;
    int span = y1 - y0;
    int nf = span & ~3;
    for (int i = 0; i < nf; i += 4, y += 4) {
      ldr(s3, y + 3); fma_self_triple(acc2, s0, s1, s2);
      ldr(s0, y + 4); fma_self_triple(acc2, s1, s2, s3);
      ldr(s1, y + 5); fma_self_triple(acc2, s2, s3, s0);
      ldr(s2, y + 6); fma_self_triple(acc2, s3, s0, s1);
    }
    int r = span & 3;
    if (r > 0) { ldr(s3, y + 3); fma_self_triple(acc2, s0, s1, s2); ++y; }
    if (r > 1) { ldr(s0, y + 3); fma_self_triple(acc2, s1, s2, s3); ++y; }
    if (r > 2) { ldr(s1, y + 3); fma_self_triple(acc2, s2, s3, s0); ++y; }
  } else if (tid < 473) {  // tail: single position x=168 (scalar, .x half)
    int b  = tid - 462;
    int y0 = (NHW * b) / 11;
    int y1 = (NHW * (b + 1)) / 11;
    float t[3][3];
#pragma unroll
    for (int r = 0; r < 3; ++r)
#pragma unroll
      for (int c = 0; c < 3; ++c) t[r][c] = X[(y0 + r) * PHP + 168 + c];
    for (int y = y0; y < y1; ++y) {
      int yn = (y + 3 <= PH - 1) ? (y + 3) : (PH - 1);
      float n0 = X[yn * PHP + 168], n1 = X[yn * PHP + 169],
            n2 = X[yn * PHP + 170];
#pragma unroll
      for (int d = 0; d < 9; ++d) acc2[d].x += t[d / 3][d % 3];
      {
        int k = 9;
#pragma unroll
        for (int d = 0; d < 9; ++d)
#pragma unroll
          for (int e = d; e < 9; ++e) {
            acc2[k].x += t[d / 3][d % 3] * t[e / 3][e % 3];
            ++k;
          }
      }
#pragma unroll
      for (int c = 0; c < 3; ++c) { t[0][c] = t[1][c]; t[1][c] = t[2][c]; }
      t[2][0] = n0; t[2][1] = n1; t[2][2] = n2;
    }
  }
  epilogue<MODE, 54>(acc2, red, covp, nc);
}

// ---- C: cross moments, strips of 2 positions; 84x6 full + 6 tail ----
__device__ __forceinline__ void mom_cross(const float* __restrict__ Pp,
                                          const float* __restrict__ Lp,
                                          float* __restrict__ covp, int nc,
                                          float* red) {
  f2v acc2[81];
#pragma unroll
  for (int k = 0; k < 81; ++k) acc2[k] = (f2v){0.f, 0.f};

  int tid = threadIdx.x;
  if (tid < 504) {
    int b = tid / 84, s = tid - b * 84;
    int x0 = 2 * s;  // 0..166
    int y0 = (NHW * b) / 6;
    int y1 = (NHW * (b + 1)) / 6;

    f2v p0[3], p1[3], p2[3], p3[3];
    f2v l0[3], l1[3], l2[3], l3[3];
    auto ldc = [&](f2v (&dp)[3], f2v (&dl)[3], int row) {
      if (row > PH - 1) row = PH - 1;
      f2v a = *(const f2v*)(Pp + row * PHP + x0);
      f2v bb = *(const f2v*)(Pp + row * PHP + x0 + 2);
      dp[0] = a; dp[1] = (f2v){a.y, bb.x}; dp[2] = bb;
      f2v c = *(const f2v*)(Lp + row * PHP + x0);
      f2v d = *(const f2v*)(Lp + row * PHP + x0 + 2);
      dl[0] = c; dl[1] = (f2v){c.y, d.x}; dl[2] = d;
    };
    ldc(p0, l0, y0); ldc(p1, l1, y0 + 1); ldc(p2, l2, y0 + 2);

    int y = y0;
    int span = y1 - y0;
    int nf = span & ~3;
    for (int i = 0; i < nf; i += 4, y += 4) {
      ldc(p3, l3, y + 3); fma_cross_triple(acc2, p0, p1, p2, l0, l1, l2);
      ldc(p0, l0, y + 4); fma_cross_triple(acc2, p1, p2, p3, l1, l2, l3);
      ldc(p1, l1, y + 5); fma_cross_triple(acc2, p2, p3, p0, l2, l3, l0);
      ldc(p2, l2, y + 6); fma_cross_triple(acc2, p3, p0, p1, l3, l0, l1);
    }
    int r = span & 3;
    if (r > 0) { ldc(p3, l3, y + 3); fma_cross_triple(acc2, p0, p1, p2, l0, l1, l2); ++y; }
    if (r > 1) { ldc(p0, l0, y + 3); fma_cross_triple(acc2, p1, p2, p3, l1, l2, l3); ++y; }
    if (r > 2) { ldc(p1, l1, y + 3); fma_cross_triple(acc2, p2, p3, p0, l2, l3, l0); ++y; }
  } else if (tid < 510) {  // tail: position x=168 (scalar)
    int b  = tid - 504;
    int y0 = (NHW * b) / 6;
    int y1 = (NHW * (b + 1)) / 6;
    float tp[3][3], tl[3][3];
#pragma unroll
    for (int r = 0; r < 3; ++r)
#pragma unroll
      for (int c = 0; c < 3; ++c) {
        tp[r][c] = Pp[(y0 + r) * PHP + 168 + c];
        tl[r][c] = Lp[(y0 + r) * PHP + 168 + c];
      }
    for (int y = y0; y < y1; ++y) {
      int yn = (y + 3 <= PH - 1) ? (y + 3) : (PH - 1);
      float np0 = Pp[yn * PHP + 168], np1 = Pp[yn * PHP + 169],
            np2 = Pp[yn * PHP + 170];
      float nl0 = Lp[yn * PHP + 168], nl1 = Lp[yn * PHP + 169],
            nl2 = Lp[yn * PHP + 170];
#pragma unroll
      for (int d = 0; d < 9; ++d)
#pragma unroll
        for (int e = 0; e < 9; ++e)
          acc2[d * 9 + e].x += tp[d / 3][d % 3] * tl[e / 3][e % 3];
#pragma unroll
      for (int c = 0; c < 3; ++c) {
        tp[0][c] = tp[1][c]; tp[1][c] = tp[2][c];
        tl[0][c] = tl[1][c]; tl[1][c] = tl[2][c];
      }
      tp[2][0] = np0; tp[2][1] = np1; tp[2][2] = np2;
      tl[2][0] = nl0; tl[2][1] = nl1; tl[2][2] = nl2;
    }
  }
  epilogue<2, 81>(acc2, red, covp, nc);
}

__global__ __launch_bounds__(512) void stage2_mom(
    const float* __restrict__ P, const float* __restrict__ L,
    float* __restrict__ covp) {
  __shared__ float red[64 * 84];  // 21.5 KB
  int nc = blockIdx.x;
  const float* Pp = P + (size_t)nc * PP2A;
  const float* Lp = L + (size_t)nc * PP2A;
  if (blockIdx.y == 0)      mom_self<0>(Lp, covp, nc, red);
  else if (blockIdx.y == 1) mom_self<1>(Pp, covp, nc, red);
  else                      mom_cross(Pp, Lp, covp, nc, red);
}

// ---------------------------------------------------------------------------
// Stage 3 (round-9 proven, verbatim): fp64 in LDS, Cholesky(la_cov+1e-5),
// triangular solve, Schur + 1e-6 I, Cholesky logdet -> covp[nc*192+190..191].
// ---------------------------------------------------------------------------
__global__ __launch_bounds__(64) void stage3_rmi(float* __restrict__ covp) {
  int nc  = blockIdx.x;
  int tid = threadIdx.x;
  const float* s = covp + (size_t)nc * 192;
  __shared__ double lc[81], pc[81], plc[81], mla[9], mpr[9];
  const double Minv = 1.0 / (double)MM;

  if (tid < 9)       mla[tid]     = (double)s[tid] * Minv;
  else if (tid < 18) mpr[tid - 9] = (double)s[tid] * Minv;
  __syncthreads();

  for (int e = tid; e < 81; e += 64) {
    int r = e / 9, c = e - 9 * (e / 9);
    int lo = r < c ? r : c, hi = r < c ? c : r;
    int k = lo * 9 - lo * (lo - 1) / 2 + (hi - lo);
    double a = (double)s[18 + k] * Minv - mla[r] * mla[c];
    if (r == c) a += 1e-5;
    lc[e] = a;
    pc[e] = (double)s[63 + k] * Minv - mpr[r] * mpr[c];
    plc[e] = (double)s[108 + e] * Minv - mpr[r] * mla[c];
  }
  __syncthreads();

  for (int j = 0; j < 9; ++j) {
    if (tid == 0) lc[j * 9 + j] = sqrt(lc[j * 9 + j]);
    __syncthreads();
    if (tid > j && tid < 9) lc[tid * 9 + j] /= lc[j * 9 + j];
    __syncthreads();
    if (tid > j && tid < 9) {
      double lij = lc[tid * 9 + j];
      for (int k = j + 1; k <= tid; ++k) lc[tid * 9 + k] -= lij * lc[k * 9 + j];
    }
    __syncthreads();
  }

  if (tid < 9) {
    int d = tid;
    for (int j = 0; j < 9; ++j) {
      double t = plc[d * 9 + j];
      for (int k = 0; k < j; ++k) t -= plc[d * 9 + k] * lc[j * 9 + k];
      plc[d * 9 + j] = t / lc[j * 9 + j];
    }
  }
  __syncthreads();

  for (int e = tid; e < 81; e += 64) {
    int r = e / 9, c = e - 9 * (e / 9);
    double a = pc[e];
    for (int f = 0; f < 9; ++f) a -= plc[r * 9 + f] * plc[c * 9 + f];
    if (r == c) a += 1e-6;
    pc[e] = a;
  }
  __syncthreads();

  for (int j = 0; j < 9; ++j) {
    if (tid == 0) pc[j * 9 + j] = sqrt(pc[j * 9 + j]);
    __syncthreads();
    if (tid > j && tid < 9) pc[tid * 9 + j] /= pc[j * 9 + j];
    __syncthreads();
    if (tid > j && tid < 9) {
      double lij = pc[tid * 9 + j];
      for (int k = j + 1; k <= tid; ++k) pc[tid * 9 + k] -= lij * pc[k * 9 + j];
    }
    __syncthreads();
  }

  if (tid == 0) {
    double sl = 0.0;
    for (int j = 0; j < 9; ++j) sl += log(pc[j * 9 + j] + 1e-8);
    *(double*)(covp + (size_t)nc * 192 + 190) = sl;  // rmi_{n,c}
  }
}

// ---------------------------------------------------------------------------
// Stage 4: reduce 76 fp64 partials -> out[0] = sum / (N * NUM_CLASSES)
// ---------------------------------------------------------------------------
__global__ __launch_bounds__(64) void stage4_reduce(
    const float* __restrict__ covp, float* __restrict__ out) {
  int tid = threadIdx.x;
  double v = 0.0;
  if (tid < NBATCH * NCLS)
    v = *(const double*)(covp + (size_t)tid * 192 + 190);
  if (tid + 64 < NBATCH * NCLS)
    v += *(const double*)(covp + (size_t)(tid + 64) * 192 + 190);
#pragma unroll
  for (int o = 32; o > 0; o >>= 1) v += __shfl_down(v, o, 64);
  if (tid == 0) out[0] = (float)(v / (double)(NBATCH * NCLS));
}

// ---------------------------------------------------------------------------
// ABLATION ROUND: stage2_mom launched 4x (idempotent; identical outputs).
// s2 = (dur_us - 72.5) / 3. Committed best remains the single-launch r9.
// ---------------------------------------------------------------------------
extern "C" void kernel_launch(void* const* d_in, const int* in_sizes, int n_in,
                              void* d_out, int out_size, void* d_ws, size_t ws_size,
                              hipStream_t stream) {
  const float* cls  = (const float*)d_in[0];
  const int* label  = (const int*)d_in[1];
  float* out = (float*)d_out;

  float* P    = (float*)d_ws;                              // 76*30096 f32
  float* L    = P + (size_t)NBATCH * NCLS * PP2A;          // 76*30096 f32
  float* covp = L + (size_t)NBATCH * NCLS * PP2A;          // 76*192 f32

  stage1_pool<<<NBATCH * PH, 512, 0, stream>>>(cls, label, P, L);
  dim3 g2(NBATCH * NCLS, 3, 1);
  stage2_mom<<<g2, 512, 0, stream>>>(P, L, covp);
  stage2_mom<<<g2, 512, 0, stream>>>(P, L, covp);
  stage2_mom<<<g2, 512, 0, stream>>>(P, L, covp);
  stage2_mom<<<g2, 512, 0, stream>>>(P, L, covp);
  stage3_rmi<<<NBATCH * NCLS, 64, 0, stream>>>(covp);
  stage4_reduce<<<1, 64, 0, stream>>>(covp, out);
}

// Round 16
// 71.938 us; speedup vs baseline: 2.3145x; 2.3145x over previous
//
#include <hip/hip_runtime.h>
#include <math.h>

// Problem constants
#define NBATCH 4
#define NCLS   19
#define HWDIM  512
#define HW     (512 * 512)      // 262144
#define PH     171              // pooled H=W
#define PHP    176              // padded row stride (16B-aligned rows)
#define PP2A   (171 * 176)      // 30096 floats per (n,c) plane
#define NHW    169              // PH - radius + 1
#define MM     (169 * 169)      // 28561

typedef float f4  __attribute__((ext_vector_type(4)));
typedef float f2v __attribute__((ext_vector_type(2)));

// ---------------------------------------------------------------------------
// Stage 1 (round-6/9 measured-best): fused softmax + one-hot + 3x3/stride-3
// avg-pool (pad=1, /9). One block per (n, pooled-row ph).
// __launch_bounds__(512,2): allow up to ~512 VGPR/wave (2 waves/EU = the 8
// waves/CU we actually run) so accP/accL/vv (~133 floats) never spill.
// ---------------------------------------------------------------------------
__global__ __launch_bounds__(512, 2) void stage1_pool(
    const float* __restrict__ cls, const int* __restrict__ label,
    float* __restrict__ P, float* __restrict__ L) {
  int n  = blockIdx.x / PH;
  int ph = blockIdx.x - n * PH;
  int col = threadIdx.x;  // input column 0..511

  float vv[3][NCLS];
  int lbs[3];
#pragma unroll
  for (int i = 0; i < 3; ++i) {
    int r = 3 * ph - 1 + i;
    bool ok = (r >= 0) && (r < HWDIM);  // wave-uniform
    if (ok) {
      lbs[i] = label[((size_t)n * HWDIM + r) * HWDIM + col];
      const float* base = cls + (size_t)n * NCLS * HW + (size_t)r * HWDIM + col;
#pragma unroll
      for (int c = 0; c < NCLS; ++c) vv[i][c] = base[(size_t)c * HW];
    } else {
      lbs[i] = -1;
#pragma unroll
      for (int c = 0; c < NCLS; ++c) vv[i][c] = 0.f;
    }
  }

  float accP[NCLS], accL[NCLS];
#pragma unroll
  for (int c = 0; c < NCLS; ++c) { accP[c] = 0.f; accL[c] = 0.f; }
#pragma unroll
  for (int i = 0; i < 3; ++i) {
    int lb = lbs[i];
    float mx = vv[i][0];
#pragma unroll
    for (int c = 1; c < NCLS; ++c) mx = fmaxf(mx, vv[i][c]);
    float se = 0.f;
    float ex[NCLS];
#pragma unroll
    for (int c = 0; c < NCLS; ++c) {
      ex[c] = __expf(vv[i][c] - mx);
      se += ex[c];
    }
    float m = (lb >= 0 && lb < NCLS) ? 1.f : 0.f;
    float inv = m / se;
#pragma unroll
    for (int c = 0; c < NCLS; ++c) {
      accP[c] += ex[c] * inv;
      accL[c] += (lb == c) ? 1.f : 0.f;  // compile-time index
    }
  }

  __shared__ float xbP[10][516];
  __shared__ float xbL[10][516];
  const float inv9 = 1.f / 9.f;
#pragma unroll
  for (int c0 = 0; c0 < NCLS; c0 += 10) {
#pragma unroll
    for (int cc = 0; cc < 10; ++cc) {
      if (c0 + cc < NCLS) {
        xbP[cc][1 + col] = accP[(c0 + cc) < NCLS ? (c0 + cc) : 0];
        xbL[cc][1 + col] = accL[(c0 + cc) < NCLS ? (c0 + cc) : 0];
        if (col == 0) { xbP[cc][0] = 0.f; xbL[cc][0] = 0.f; }
      }
    }
    __syncthreads();
    if (col < PH) {
      int pw = col;
#pragma unroll
      for (int cc = 0; cc < 10; ++cc) {
        if (c0 + cc < NCLS) {
          int c = c0 + cc;
          float sP = xbP[cc][3 * pw] + xbP[cc][3 * pw + 1] + xbP[cc][3 * pw + 2];
          float sL = xbL[cc][3 * pw] + xbL[cc][3 * pw + 1] + xbL[cc][3 * pw + 2];
          size_t o = ((size_t)(n * NCLS + c)) * PP2A + (size_t)ph * PHP + pw;
          P[o] = sP * inv9;
          L[o] = sL * inv9;
        }
      }
    } else if (col < PHP) {
#pragma unroll
      for (int cc = 0; cc < 10; ++cc) {
        if (c0 + cc < NCLS) {
          int c = c0 + cc;
          size_t o = ((size_t)(n * NCLS + c)) * PP2A + (size_t)ph * PHP + col;
          P[o] = 0.f;
          L[o] = 0.f;
        }
      }
    }
    __syncthreads();
  }
}

// ---------------------------------------------------------------------------
// Stage 2 (round-9 structure + __launch_bounds__(512,2) SPILL FIX):
// packed-fp32 moments with zero-move 4-slot window rotation. The C-part needs
// 162 VGPRs of accumulator alone; prior builds (VGPR_Count 60-92) spilled them
// to scratch, making every variant scratch-BW-bound (~31 us invariant).
// (512,2) allows ~512 VGPR/wave at the 8-waves/CU occupancy we already run.
// Parts: 0: la*la+sum(la) | 1: pr*pr+sum(pr) | 2: pr[d]*la[e].
// Record per nc (stride 192 f32): [0..8] sum la | [9..17] sum pr |
// [18..62] la*la | [63..107] pr*pr | [108..188] pr*la | [190..191] dbl logdet
// ---------------------------------------------------------------------------
template <int MODE, int NA>
__device__ __forceinline__ void epilogue(const f2v (&acc2)[NA], float* red,
                                         float* __restrict__ covp, int nc) {
  int lane = threadIdx.x & 63;
  int wid  = threadIdx.x >> 6;  // 8 waves
#pragma unroll
  for (int k = 0; k < NA; ++k) {
    float v = acc2[k].x + acc2[k].y;
    v += __shfl_down(v, 32, 64);
    v += __shfl_down(v, 16, 64);
    v += __shfl_down(v, 8, 64);
    if (lane < 8) red[(wid * 8 + lane) * 84 + k] = v;
  }
  __syncthreads();
  int tid = threadIdx.x;
  if (tid < NA) {
    float sm = 0.f;
#pragma unroll
    for (int w = 0; w < 64; ++w) sm += red[w * 84 + tid];
    int off;
    if (MODE == 0)      off = (tid < 9) ? tid : 18 + (tid - 9);
    else if (MODE == 1) off = (tid < 9) ? 9 + tid : 63 + (tid - 9);
    else                off = 108 + tid;
    covp[(size_t)nc * 192 + off] = sm;
  }
}

__device__ __forceinline__ void fma_self_triple(f2v (&acc2)[54],
    const f2v (&r0)[5], const f2v (&r1)[5], const f2v (&r2)[5]) {
#define RP(d, off) ((d) < 3 ? r0[(d) % 3 + (off)] \
                 : (d) < 6 ? r1[(d) % 3 + (off)] : r2[(d) % 3 + (off)])
#pragma unroll
  for (int d = 0; d < 9; ++d) {
    acc2[d] += RP(d, 0);
    acc2[d] += RP(d, 2);
  }
  {
    int k = 9;
#pragma unroll
    for (int d = 0; d < 9; ++d)
#pragma unroll
      for (int e = d; e < 9; ++e) {
        acc2[k] += RP(d, 0) * RP(e, 0);
        acc2[k] += RP(d, 2) * RP(e, 2);
        ++k;
      }
  }
#undef RP
}

__device__ __forceinline__ void fma_cross_triple(f2v (&acc2)[81],
    const f2v (&p0)[3], const f2v (&p1)[3], const f2v (&p2)[3],
    const f2v (&l0)[3], const f2v (&l1)[3], const f2v (&l2)[3]) {
#define QP(d) ((d) < 3 ? p0[(d) % 3] : (d) < 6 ? p1[(d) % 3] : p2[(d) % 3])
#define QL(e) ((e) < 3 ? l0[(e) % 3] : (e) < 6 ? l1[(e) % 3] : l2[(e) % 3])
#pragma unroll
  for (int d = 0; d < 9; ++d)
#pragma unroll
    for (int e = 0; e < 9; ++e)
      acc2[d * 9 + e] += QP(d) * QL(e);
#undef QP
#undef QL
}

// ---- A/B: self moments, strips of 4 positions; 42x11 full + 11 tail ----
template <int MODE>
__device__ __forceinline__ void mom_self(const float* __restrict__ X,
                                         float* __restrict__ covp, int nc,
                                         float* red) {
  f2v acc2[54];
#pragma unroll
  for (int k = 0; k < 54; ++k) acc2[k] = (f2v){0.f, 0.f};

  int tid = threadIdx.x;
  if (tid < 462) {
    int b = tid / 42, s = tid - b * 42;
    int x0 = 4 * s;  // 0..164
    int y0 = (NHW * b) / 11;
    int y1 = (NHW * (b + 1)) / 11;

    f2v s0[5], s1[5], s2[5], s3[5];
    auto ldr = [&](f2v (&dst)[5], int row) {
      if (row > PH - 1) row = PH - 1;  // clamp; clamped rows never consumed
      f4  a  = *(const f4*)(X + row * PHP + x0);
      f2v bb = *(const f2v*)(X + row * PHP + x0 + 4);
      dst[0] = (f2v){a.x, a.y}; dst[1] = (f2v){a.y, a.z};
      dst[2] = (f2v){a.z, a.w}; dst[3] = (f2v){a.w, bb.x};
      dst[4] = bb;
    };
    ldr(s0, y0); ldr(s1, y0 + 1); ldr(s2, y0 + 2);

    int y = y0;
    int span = y1 - y0;
    int nf = span & ~3;
    for (int i = 0; i < nf; i += 4, y += 4) {
      ldr(s3, y + 3); fma_self_triple(acc2, s0, s1, s2);
      ldr(s0, y + 4); fma_self_triple(acc2, s1, s2, s3);
      ldr(s1, y + 5); fma_self_triple(acc2, s2, s3, s0);
      ldr(s2, y + 6); fma_self_triple(acc2, s3, s0, s1);
    }
    int r = span & 3;
    if (r > 0) { ldr(s3, y + 3); fma_self_triple(acc2, s0, s1, s2); ++y; }
    if (r > 1) { ldr(s0, y + 3); fma_self_triple(acc2, s1, s2, s3); ++y; }
    if (r > 2) { ldr(s1, y + 3); fma_self_triple(acc2, s2, s3, s0); ++y; }
  } else if (tid < 473) {  // tail: single position x=168 (scalar, .x half)
    int b  = tid - 462;
    int y0 = (NHW * b) / 11;
    int y1 = (NHW * (b + 1)) / 11;
    float t[3][3];
#pragma unroll
    for (int r = 0; r < 3; ++r)
#pragma unroll
      for (int c = 0; c < 3; ++c) t[r][c] = X[(y0 + r) * PHP + 168 + c];
    for (int y = y0; y < y1; ++y) {
      int yn = (y + 3 <= PH - 1) ? (y + 3) : (PH - 1);
      float n0 = X[yn * PHP + 168], n1 = X[yn * PHP + 169],
            n2 = X[yn * PHP + 170];
#pragma unroll
      for (int d = 0; d < 9; ++d) acc2[d].x += t[d / 3][d % 3];
      {
        int k = 9;
#pragma unroll
        for (int d = 0; d < 9; ++d)
#pragma unroll
          for (int e = d; e < 9; ++e) {
            acc2[k].x += t[d / 3][d % 3] * t[e / 3][e % 3];
            ++k;
          }
      }
#pragma unroll
      for (int c = 0; c < 3; ++c) { t[0][c] = t[1][c]; t[1][c] = t[2][c]; }
      t[2][0] = n0; t[2][1] = n1; t[2][2] = n2;
    }
  }
  epilogue<MODE, 54>(acc2, red, covp, nc);
}

// ---- C: cross moments, strips of 2 positions; 84x6 full + 6 tail ----
__device__ __forceinline__ void mom_cross(const float* __restrict__ Pp,
                                          const float* __restrict__ Lp,
                                          float* __restrict__ covp, int nc,
                                          float* red) {
  f2v acc2[81];
#pragma unroll
  for (int k = 0; k < 81; ++k) acc2[k] = (f2v){0.f, 0.f};

  int tid = threadIdx.x;
  if (tid < 504) {
    int b = tid / 84, s = tid - b * 84;
    int x0 = 2 * s;  // 0..166
    int y0 = (NHW * b) / 6;
    int y1 = (NHW * (b + 1)) / 6;

    f2v p0[3], p1[3], p2[3], p3[3];
    f2v l0[3], l1[3], l2[3], l3[3];
    auto ldc = [&](f2v (&dp)[3], f2v (&dl)[3], int row) {
      if (row > PH - 1) row = PH - 1;
      f2v a = *(const f2v*)(Pp + row * PHP + x0);
      f2v bb = *(const f2v*)(Pp + row * PHP + x0 + 2);
      dp[0] = a; dp[1] = (f2v){a.y, bb.x}; dp[2] = bb;
      f2v c = *(const f2v*)(Lp + row * PHP + x0);
      f2v d = *(const f2v*)(Lp + row * PHP + x0 + 2);
      dl[0] = c; dl[1] = (f2v){c.y, d.x}; dl[2] = d;
    };
    ldc(p0, l0, y0); ldc(p1, l1, y0 + 1); ldc(p2, l2, y0 + 2);

    int y = y0;
    int span = y1 - y0;
    int nf = span & ~3;
    for (int i = 0; i < nf; i += 4, y += 4) {
      ldc(p3, l3, y + 3); fma_cross_triple(acc2, p0, p1, p2, l0, l1, l2);
      ldc(p0, l0, y + 4); fma_cross_triple(acc2, p1, p2, p3, l1, l2, l3);
      ldc(p1, l1, y + 5); fma_cross_triple(acc2, p2, p3, p0, l2, l3, l0);
      ldc(p2, l2, y + 6); fma_cross_triple(acc2, p3, p0, p1, l3, l0, l1);
    }
    int r = span & 3;
    if (r > 0) { ldc(p3, l3, y + 3); fma_cross_triple(acc2, p0, p1, p2, l0, l1, l2); ++y; }
    if (r > 1) { ldc(p0, l0, y + 3); fma_cross_triple(acc2, p1, p2, p3, l1, l2, l3); ++y; }
    if (r > 2) { ldc(p1, l1, y + 3); fma_cross_triple(acc2, p2, p3, p0, l2, l3, l0); ++y; }
  } else if (tid < 510) {  // tail: position x=168 (scalar)
    int b  = tid - 504;
    int y0 = (NHW * b) / 6;
    int y1 = (NHW * (b + 1)) / 6;
    float tp[3][3], tl[3][3];
#pragma unroll
    for (int r = 0; r < 3; ++r)
#pragma unroll
      for (int c = 0; c < 3; ++c) {
        tp[r][c] = Pp[(y0 + r) * PHP + 168 + c];
        tl[r][c] = Lp[(y0 + r) * PHP + 168 + c];
      }
    for (int y = y0; y < y1; ++y) {
      int yn = (y + 3 <= PH - 1) ? (y + 3) : (PH - 1);
      float np0 = Pp[yn * PHP + 168], np1 = Pp[yn * PHP + 169],
            np2 = Pp[yn * PHP + 170];
      float nl0 = Lp[yn * PHP + 168], nl1 = Lp[yn * PHP + 169],
            nl2 = Lp[yn * PHP + 170];
#pragma unroll
      for (int d = 0; d < 9; ++d)
#pragma unroll
        for (int e = 0; e < 9; ++e)
          acc2[d * 9 + e].x += tp[d / 3][d % 3] * tl[e / 3][e % 3];
#pragma unroll
      for (int c = 0; c < 3; ++c) {
        tp[0][c] = tp[1][c]; tp[1][c] = tp[2][c];
        tl[0][c] = tl[1][c]; tl[1][c] = tl[2][c];
      }
      tp[2][0] = np0; tp[2][1] = np1; tp[2][2] = np2;
      tl[2][0] = nl0; tl[2][1] = nl1; tl[2][2] = nl2;
    }
  }
  epilogue<2, 81>(acc2, red, covp, nc);
}

__global__ __launch_bounds__(512, 2) void stage2_mom(
    const float* __restrict__ P, const float* __restrict__ L,
    float* __restrict__ covp) {
  __shared__ float red[64 * 84];  // 21.5 KB
  int nc = blockIdx.x;
  const float* Pp = P + (size_t)nc * PP2A;
  const float* Lp = L + (size_t)nc * PP2A;
  if (blockIdx.y == 0)      mom_self<0>(Lp, covp, nc, red);
  else if (blockIdx.y == 1) mom_self<1>(Pp, covp, nc, red);
  else                      mom_cross(Pp, Lp, covp, nc, red);
}

// ---------------------------------------------------------------------------
// Stage 3 (round-9 proven, verbatim): fp64 in LDS, Cholesky(la_cov+1e-5),
// triangular solve, Schur + 1e-6 I, Cholesky logdet -> covp[nc*192+190..191].
// ---------------------------------------------------------------------------
__global__ __launch_bounds__(64) void stage3_rmi(float* __restrict__ covp) {
  int nc  = blockIdx.x;
  int tid = threadIdx.x;
  const float* s = covp + (size_t)nc * 192;
  __shared__ double lc[81], pc[81], plc[81], mla[9], mpr[9];
  const double Minv = 1.0 / (double)MM;

  if (tid < 9)       mla[tid]     = (double)s[tid] * Minv;
  else if (tid < 18) mpr[tid - 9] = (double)s[tid] * Minv;
  __syncthreads();

  for (int e = tid; e < 81; e += 64) {
    int r = e / 9, c = e - 9 * (e / 9);
    int lo = r < c ? r : c, hi = r < c ? c : r;
    int k = lo * 9 - lo * (lo - 1) / 2 + (hi - lo);
    double a = (double)s[18 + k] * Minv - mla[r] * mla[c];
    if (r == c) a += 1e-5;
    lc[e] = a;
    pc[e] = (double)s[63 + k] * Minv - mpr[r] * mpr[c];
    plc[e] = (double)s[108 + e] * Minv - mpr[r] * mla[c];
  }
  __syncthreads();

  for (int j = 0; j < 9; ++j) {
    if (tid == 0) lc[j * 9 + j] = sqrt(lc[j * 9 + j]);
    __syncthreads();
    if (tid > j && tid < 9) lc[tid * 9 + j] /= lc[j * 9 + j];
    __syncthreads();
    if (tid > j && tid < 9) {
      double lij = lc[tid * 9 + j];
      for (int k = j + 1; k <= tid; ++k) lc[tid * 9 + k] -= lij * lc[k * 9 + j];
    }
    __syncthreads();
  }

  if (tid < 9) {
    int d = tid;
    for (int j = 0; j < 9; ++j) {
      double t = plc[d * 9 + j];
      for (int k = 0; k < j; ++k) t -= plc[d * 9 + k] * lc[j * 9 + k];
      plc[d * 9 + j] = t / lc[j * 9 + j];
    }
  }
  __syncthreads();

  for (int e = tid; e < 81; e += 64) {
    int r = e / 9, c = e - 9 * (e / 9);
    double a = pc[e];
    for (int f = 0; f < 9; ++f) a -= plc[r * 9 + f] * plc[c * 9 + f];
    if (r == c) a += 1e-6;
    pc[e] = a;
  }
  __syncthreads();

  for (int j = 0; j < 9; ++j) {
    if (tid == 0) pc[j * 9 + j] = sqrt(pc[j * 9 + j]);
    __syncthreads();
    if (tid > j && tid < 9) pc[tid * 9 + j] /= pc[j * 9 + j];
    __syncthreads();
    if (tid > j && tid < 9) {
      double lij = pc[tid * 9 + j];
      for (int k = j + 1; k <= tid; ++k) pc[tid * 9 + k] -= lij * pc[k * 9 + j];
    }
    __syncthreads();
  }

  if (tid == 0) {
    double sl = 0.0;
    for (int j = 0; j < 9; ++j) sl += log(pc[j * 9 + j] + 1e-8);
    *(double*)(covp + (size_t)nc * 192 + 190) = sl;  // rmi_{n,c}
  }
}

// ---------------------------------------------------------------------------
// Stage 4: reduce 76 fp64 partials -> out[0] = sum / (N * NUM_CLASSES)
// ---------------------------------------------------------------------------
__global__ __launch_bounds__(64) void stage4_reduce(
    const float* __restrict__ covp, float* __restrict__ out) {
  int tid = threadIdx.x;
  double v = 0.0;
  if (tid < NBATCH * NCLS)
    v = *(const double*)(covp + (size_t)tid * 192 + 190);
  if (tid + 64 < NBATCH * NCLS)
    v += *(const double*)(covp + (size_t)(tid + 64) * 192 + 190);
#pragma unroll
  for (int o = 32; o > 0; o >>= 1) v += __shfl_down(v, o, 64);
  if (tid == 0) out[0] = (float)(v / (double)(NBATCH * NCLS));
}

// ---------------------------------------------------------------------------
extern "C" void kernel_launch(void* const* d_in, const int* in_sizes, int n_in,
                              void* d_out, int out_size, void* d_ws, size_t ws_size,
                              hipStream_t stream) {
  const float* cls  = (const float*)d_in[0];
  const int* label  = (const int*)d_in[1];
  float* out = (float*)d_out;

  float* P    = (float*)d_ws;                              // 76*30096 f32
  float* L    = P + (size_t)NBATCH * NCLS * PP2A;          // 76*30096 f32
  float* covp = L + (size_t)NBATCH * NCLS * PP2A;          // 76*192 f32

  stage1_pool<<<NBATCH * PH, 512, 0, stream>>>(cls, label, P, L);
  dim3 g2(NBATCH * NCLS, 3, 1);
  stage2_mom<<<g2, 512, 0, stream>>>(P, L, covp);
  stage3_rmi<<<NBATCH * NCLS, 64, 0, stream>>>(covp);
  stage4_reduce<<<1, 64, 0, stream>>>(covp, out);
}